// Round 1
// baseline (129.517 us; speedup 1.0000x reference)
//
#include <hip/hip_runtime.h>
#include <hip/hip_bf16.h>

// Embedding-bag (table-wise, mean mode).
//   weights: [T*R, D] fp32 (flat; indices are global row ids)
//   indices: [n] int32 global row ids
//   offsets: [T*B] int32 bag starts (sorted)
//   out:     [B, T*D] fp32 ; bag seg = t*B + b -> out[b, t*D .. t*D+D)
//
// 32 lanes per bag, float4 per lane (D=128 -> 32*4 dims). Each iteration the
// bag's 32 lanes read one contiguous 512B row (fully coalesced gather).

#ifndef EMB_T
#define EMB_T 8   // number of tables (problem constant)
#endif

__global__ __launch_bounds__(256) void emb_bag_mean_kernel(
    const float* __restrict__ weights,
    const int*   __restrict__ indices,
    const int*   __restrict__ offsets,
    float*       __restrict__ out,
    int num_bags,   // T*B
    int batch,      // B
    int D,          // 128
    int n)          // total index count
{
    int gtid = blockIdx.x * blockDim.x + threadIdx.x;
    int bag  = gtid >> 5;          // 32 lanes per bag
    int lane = gtid & 31;
    if (bag >= num_bags) return;

    int start = offsets[bag];
    int end   = (bag + 1 < num_bags) ? offsets[bag + 1] : n;
    int cnt   = end - start;

    float4 acc = make_float4(0.f, 0.f, 0.f, 0.f);

    int l = start;
    // 4-deep unroll: 4 independent row gathers in flight per thread
    for (; l + 4 <= end; l += 4) {
        int r0 = indices[l + 0];
        int r1 = indices[l + 1];
        int r2 = indices[l + 2];
        int r3 = indices[l + 3];
        const float4* p0 = reinterpret_cast<const float4*>(weights + (size_t)r0 * D);
        const float4* p1 = reinterpret_cast<const float4*>(weights + (size_t)r1 * D);
        const float4* p2 = reinterpret_cast<const float4*>(weights + (size_t)r2 * D);
        const float4* p3 = reinterpret_cast<const float4*>(weights + (size_t)r3 * D);
        float4 v0 = p0[lane];
        float4 v1 = p1[lane];
        float4 v2 = p2[lane];
        float4 v3 = p3[lane];
        acc.x += v0.x + v1.x + v2.x + v3.x;
        acc.y += v0.y + v1.y + v2.y + v3.y;
        acc.z += v0.z + v1.z + v2.z + v3.z;
        acc.w += v0.w + v1.w + v2.w + v3.w;
    }
    for (; l < end; ++l) {
        int r = indices[l];
        const float4* p = reinterpret_cast<const float4*>(weights + (size_t)r * D);
        float4 v = p[lane];
        acc.x += v.x; acc.y += v.y; acc.z += v.z; acc.w += v.w;
    }

    float inv = 1.0f / (float)(cnt > 0 ? cnt : 1);
    acc.x *= inv; acc.y *= inv; acc.z *= inv; acc.w *= inv;

    // bag = t*batch + b  ->  out[b * (T*D) + t*D + lane*4]
    int t = bag / batch;
    int b = bag - t * batch;
    size_t obase = (size_t)b * ((size_t)EMB_T * D) + (size_t)t * D;
    float4* op = reinterpret_cast<float4*>(out + obase);
    op[lane] = acc;
}

extern "C" void kernel_launch(void* const* d_in, const int* in_sizes, int n_in,
                              void* d_out, int out_size, void* d_ws, size_t ws_size,
                              hipStream_t stream) {
    const float* weights = (const float*)d_in[0];
    const int*   indices = (const int*)d_in[1];
    const int*   offsets = (const int*)d_in[2];
    float*       out     = (float*)d_out;

    int n        = in_sizes[1];           // T*B*L
    int num_bags = in_sizes[2];           // T*B
    int D        = out_size / num_bags;   // 128
    int batch    = num_bags / EMB_T;      // B

    int total_threads = num_bags * 32;
    int block = 256;
    int grid  = (total_threads + block - 1) / block;

    hipLaunchKernelGGL(emb_bag_mean_kernel, dim3(grid), dim3(block), 0, stream,
                       weights, indices, offsets, out, num_bags, batch, D, n);
}